// Round 24
// baseline (95.844 us; speedup 1.0000x reference)
//
#include <hip/hip_runtime.h>
#include <hip/hip_bf16.h>
#include <hip/hip_fp16.h>

typedef float f32x4 __attribute__((ext_vector_type(4)));
typedef unsigned int u32;
typedef u32 u32x4 __attribute__((ext_vector_type(4)));
typedef __bf16 bf16x8 __attribute__((ext_vector_type(8)));
typedef short s16x8 __attribute__((ext_vector_type(8)));
typedef unsigned short u16;

#define HWSZ 16384
#define NPIX 131072

// ws byte offsets
#define XT_OFF    0u          // u16(bf16)[NPIX*64]  x transposed to NHWC (16.78 MB)
#define YB_OFF    16777216u   // u16(bf16)[NPIX*64]  pre-BN activation, NCHW (16.78 MB)
#define PART_OFF  33554432u   // float[2048*128]  per-block BN partials (1 MB)
#define WB_OFF    42991616u   // u16(bf16)[64*576]  deform_w, [o][k2*64+c]
#define STATS_OFF 43106816u   // float[256]: (unused)[128], scale[64], shift[64]
#define WO_OFF    43107840u   // u16(bf16)[32*576]  offset_w padded, [oc][k2*64+c]

__device__ inline u32 pkbf(float lo, float hi) {
  u16 l = __builtin_bit_cast(u16, __float2bfloat16(lo));
  u16 h = __builtin_bit_cast(u16, __float2bfloat16(hi));
  return (u32)l | ((u32)h << 16);
}
__device__ inline float bflo(u32 u) { return __builtin_bit_cast(float, u << 16); }
__device__ inline float bfhi(u32 u) { return __builtin_bit_cast(float, u & 0xFFFF0000u); }

// ---- prep: reorder/convert weights to bf16 ----
__global__ void kprep(const float* __restrict__ dw, const float* __restrict__ ow,
                      u16* __restrict__ Wb, u16* __restrict__ Wo) {
  int t = blockIdx.x * 256 + threadIdx.x;
  if (t < 36864) {                      // deform_w (64,64,3,3) -> Wb[o][k2*64+c] bf16
    int o = t / 576, r = t % 576;
    int c = r / 9, k2 = r % 9;
    __hip_bfloat16 h = __float2bfloat16(dw[t]);
    Wb[o * 576 + k2 * 64 + c] = __builtin_bit_cast(u16, h);
  } else if (t < 55296) {               // offset_w (18,64,3,3) -> Wo[oc][k2*64+c], pad to 32
    int t2 = t - 36864;
    int oc = t2 / 576, r = t2 % 576;
    int c = r / 9, k2 = r % 9;
    float v = (oc < 18) ? ow[(oc * 64 + c) * 9 + k2] : 0.f;
    __hip_bfloat16 h = __float2bfloat16(v);
    Wo[oc * 576 + k2 * 64 + c] = __builtin_bit_cast(u16, h);
  }
}

// ---- NCHW f32 -> NHWC bf16 transpose of x (vectorized 16B stores) ----
__global__ void ktrans(const float* __restrict__ x, u16* __restrict__ xt) {
  __shared__ float tile[64][65];
  int blk = blockIdx.x;
  int b = blk >> 8, hwT = (blk & 255) * 64;
  int tid = threadIdx.x;
  int tx = tid & 63, ty = tid >> 6;
  const float* xp = x + (size_t)b * 64 * HWSZ;
#pragma unroll
  for (int r = 0; r < 16; ++r) {
    int c = r * 4 + ty;
    tile[c][tx] = xp[c * HWSZ + hwT + tx];
  }
  __syncthreads();
  u16* xo = xt + ((size_t)b * HWSZ + hwT) * 64;
  int o8 = (tid & 7) * 8;
#pragma unroll
  for (int r = 0; r < 2; ++r) {
    int hwl = r * 32 + (tid >> 3);
    u32x4 out;
#pragma unroll
    for (int j = 0; j < 4; ++j)
      out[j] = pkbf(tile[o8 + 2 * j][hwl], tile[o8 + 2 * j + 1][hwl]);
    *(u32x4*)&xo[(size_t)hwl * 64 + o8] = out;
  }
}

// ---- fused, 2-taps-per-stage pipeline, 64-px tile ----
// block: 256 thr = 4 waves; 5 stages/phase -> 10 barriers total (was 18)
// LDS: S2 32768 + mWp 4608 + mPos 2304 = 39680 B -> 4 blocks/CU
__global__ __launch_bounds__(256, 4) void kmain(
    const u16* __restrict__ xt, const u16* __restrict__ Wo,
    const float* __restrict__ offb, const u16* __restrict__ Wb,
    const float* __restrict__ db, u16* __restrict__ yb,
    float* __restrict__ part) {
  __shared__ u16 S2[2][2][64 * 64];    // [dbuf][tap-in-stage][px*64+ch], swizzled
  __shared__ u32 mWp[576 * 2];         // per (pix,tap): f16x2 {w00,w01},{w10,w11}
  __shared__ u32 mPos[576];            // pixel_byte(×128) | dxs | dys<<1
  float* OFFT = (float*)&S2[0][0][0];  // [64][20] floats, aliases S2 (phase-separated)
  int tid = threadIdx.x;
  int lane = tid & 63, wid = tid >> 6;
  int bid = blockIdx.x;
  int batch = bid & 7, tilei = bid >> 3;
  int base = (batch << 14) + tilei * 64;
  int b = batch;
  int hw0 = base & 16383;
  int h0 = hw0 >> 7, w0 = hw0 & 127;   // 64-px tile lies within row h0

  int oct = lane & 7;
  int p0 = wid * 8 + (lane >> 3);      // this thread's pixels: p0, p0+32
  int oct16 = oct << 4, oct8 = oct << 3;
  int q8 = (lane >> 4) * 8;
  const char* xb = (const char*)xt;

  // ---- phase 1: offset-conv GEMM, 2 taps per stage ----
  int ocb2 = wid & 1, pxb2 = (wid >> 1) * 2;
  int orow_o = ocb2 * 16 + (lane & 15);
  f32x4 acco[2];
  acco[0] = {0.f, 0.f, 0.f, 0.f};
  acco[1] = {0.f, 0.f, 0.f, 0.f};
#pragma unroll
  for (int s = 0; s < 5; ++s) {
    int ntap = (s < 4) ? 2 : 1;
#pragma unroll
    for (int ti = 0; ti < 2; ++ti) {
      if (ti < ntap) {
        int k = 2 * s + ti;
#pragma unroll
        for (int pi = 0; pi < 2; ++pi) {
          int pp = p0 + pi * 32;
          int yy = h0 - 1 + k / 3, xx = w0 + pp - 1 + k % 3;
          bool v = ((unsigned)yy < 128u) && ((unsigned)xx < 128u);
          const char* pb =
              v ? xb + (size_t)(((b << 14) + yy * 128 + xx) * 128) + oct16 : xb;
          u32x4 g = *(const u32x4*)pb;
          u32 msk = v ? 0xFFFFFFFFu : 0u;
          u32x4 out;
#pragma unroll
          for (int j = 0; j < 4; ++j) out[j] = g[j] & msk;
          *(u32x4*)&S2[s & 1][ti][(pp * 64 + oct8) ^ ((pp & 7) << 3)] = out;
        }
      }
    }
    __syncthreads();
#pragma unroll
    for (int ti = 0; ti < 2; ++ti) {
      if (ti < ntap) {
#pragma unroll
        for (int h = 0; h < 2; ++h) {
          int kc = (2 * s + ti) * 2 + h;
          s16x8 a = *(const s16x8*)(Wo + orow_o * 576 + kc * 32 + q8);
#pragma unroll
          for (int t2 = 0; t2 < 2; ++t2) {
            int row = (pxb2 + t2) * 16 + (lane & 15);
            int idx = (row * 64 + h * 32 + q8) ^ ((row & 7) << 3);
            bf16x8 bb =
                __builtin_bit_cast(bf16x8, *(const s16x8*)&S2[s & 1][ti][idx]);
            acco[t2] = __builtin_amdgcn_mfma_f32_16x16x32_bf16(
                __builtin_bit_cast(bf16x8, a), bb, acco[t2], 0, 0, 0);
          }
        }
      }
    }
  }
  __syncthreads();                     // S2 dead; OFFT may now be written

  // ---- offs -> OFFT (aliases S2) ----
#pragma unroll
  for (int t2 = 0; t2 < 2; ++t2) {
    int pixl = (pxb2 + t2) * 16 + (lane & 15);
    int ocb = ocb2 * 16 + (lane >> 4) * 4;
#pragma unroll
    for (int r = 0; r < 4; ++r) {
      int oc = ocb + r;
      if (oc < 18) OFFT[pixl * 20 + oc] = acco[t2][r] + offb[oc];
    }
  }
  __syncthreads();

  // ---- meta: per-(pixel,tap), 576 tasks ----
  for (int t = tid; t < 576; t += 256) {
    int tp = t / 9, k2 = t - tp * 9;
    int pix = base + tp;
    int hw = pix & 16383;
    int hh = hw >> 7, ww = hw & 127;
    float dy = OFFT[tp * 20 + 2 * k2];
    float dx = OFFT[tp * 20 + 2 * k2 + 1];
    float sy = (float)(hh - 1 + k2 / 3) + dy;
    float sx = (float)(ww - 1 + k2 % 3) + dx;
    float fy = floorf(sy), fx = floorf(sx);
    int y0 = (int)fy, x0 = (int)fx;
    float wy1 = sy - fy, wx1 = sx - fx;
    float ay0 = ((unsigned)y0 < 128u) ? 1.f - wy1 : 0.f;
    float ay1 = ((unsigned)(y0 + 1) < 128u) ? wy1 : 0.f;
    float ax0 = ((unsigned)x0 < 128u) ? 1.f - wx1 : 0.f;
    float ax1 = ((unsigned)(x0 + 1) < 128u) ? wx1 : 0.f;
    int y0c = min(max(y0, 0), 127), x0c = min(max(x0, 0), 127);
    int dys = min(max(y0 + 1, 0), 127) - y0c;
    int dxs = min(max(x0 + 1, 0), 127) - x0c;
    mWp[t * 2]     = __builtin_bit_cast(u32, __floats2half2_rn(ay0 * ax0, ay0 * ax1));
    mWp[t * 2 + 1] = __builtin_bit_cast(u32, __floats2half2_rn(ay1 * ax0, ay1 * ax1));
    mPos[t] = (u32)(((b << 14) + y0c * 128 + x0c) * 128) | (u32)dxs | ((u32)dys << 1);
  }
  __syncthreads();                     // meta done; S2 (OFFT) may be overwritten

  // ---- phase 2: deform GEMM, 2 taps per stage ----
  f32x4 acc[4];
#pragma unroll
  for (int nb = 0; nb < 4; ++nb) acc[nb] = {0.f, 0.f, 0.f, 0.f};
  int orow_d = wid * 16 + (lane & 15);
#pragma unroll
  for (int s = 0; s < 5; ++s) {
    int ntap = (s < 4) ? 2 : 1;
#pragma unroll
    for (int ti = 0; ti < 2; ++ti) {
      if (ti < ntap) {
        int k = 2 * s + ti;
#pragma unroll
        for (int pi = 0; pi < 2; ++pi) {
          int pp = p0 + pi * 32;
          int t = pp * 9 + k;
          u32 wlo = mWp[t * 2], whi = mWp[t * 2 + 1];
          u32 pm = mPos[t];
          u32 dxB = (pm & 1u) << 7;    // 128 B x-step
          u32 dyB = (pm & 2u) << 13;   // 16384 B y-step
          const char* pb = xb + (pm & 0xFFFFFF80u) + oct16;
          u32x4 c00 = *(const u32x4*)pb;
          u32x4 c01 = *(const u32x4*)(pb + dxB);
          u32x4 c10 = *(const u32x4*)(pb + dyB);
          u32x4 c11 = *(const u32x4*)(pb + dyB + dxB);
          __half2 hl = __builtin_bit_cast(__half2, wlo);
          __half2 hh2 = __builtin_bit_cast(__half2, whi);
          float w00 = __low2float(hl), w01 = __high2float(hl);
          float w10 = __low2float(hh2), w11 = __high2float(hh2);
          u32x4 out;
#pragma unroll
          for (int j = 0; j < 4; ++j) {
            float sL = fmaf(w11, bflo(c11[j]), fmaf(w10, bflo(c10[j]),
                       fmaf(w01, bflo(c01[j]), w00 * bflo(c00[j]))));
            float sH = fmaf(w11, bfhi(c11[j]), fmaf(w10, bfhi(c10[j]),
                       fmaf(w01, bfhi(c01[j]), w00 * bfhi(c00[j]))));
            out[j] = pkbf(sL, sH);
          }
          *(u32x4*)&S2[s & 1][ti][(pp * 64 + oct8) ^ ((pp & 7) << 3)] = out;
        }
      }
    }
    __syncthreads();
#pragma unroll
    for (int ti = 0; ti < 2; ++ti) {
      if (ti < ntap) {
#pragma unroll
        for (int h = 0; h < 2; ++h) {
          int kc = (2 * s + ti) * 2 + h;
          s16x8 a = *(const s16x8*)(Wb + orow_d * 576 + kc * 32 + q8);
#pragma unroll
          for (int nb = 0; nb < 4; ++nb) {
            int row = nb * 16 + (lane & 15);
            int idx = (row * 64 + h * 32 + q8) ^ ((row & 7) << 3);
            bf16x8 bb =
                __builtin_bit_cast(bf16x8, *(const s16x8*)&S2[s & 1][ti][idx]);
            acc[nb] = __builtin_amdgcn_mfma_f32_16x16x32_bf16(
                __builtin_bit_cast(bf16x8, a), bb, acc[nb], 0, 0, 0);
          }
        }
      }
    }
  }

  // ---- epilogue: yb (bf16, NCHW) write + per-block BN partials (no atomics) ----
  int obase = wid * 16 + (lane >> 4) * 4;
  float s1[4] = {0, 0, 0, 0}, s2[4] = {0, 0, 0, 0};
#pragma unroll
  for (int nb = 0; nb < 4; ++nb) {
    int pix = base + nb * 16 + (lane & 15);
    int hw = pix & 16383;
    u16* yp = yb + (size_t)b * (64 * HWSZ) + hw;
#pragma unroll
    for (int r = 0; r < 4; ++r) {
      int o = obase + r;
      float v = acc[nb][r] + db[o];
      yp[(size_t)o * HWSZ] = __builtin_bit_cast(u16, __float2bfloat16(v));
      s1[r] += v;
      s2[r] += v * v;
    }
  }
#pragma unroll
  for (int m = 1; m < 16; m <<= 1) {
#pragma unroll
    for (int r = 0; r < 4; ++r) {
      s1[r] += __shfl_xor(s1[r], m, 64);
      s2[r] += __shfl_xor(s2[r], m, 64);
    }
  }
  if ((lane & 15) == 0) {
    float* pp = part + (size_t)bid * 128;
#pragma unroll
    for (int r = 0; r < 4; ++r) {
      pp[obase + r] = s1[r];
      pp[64 + obase + r] = s2[r];
    }
  }
}

// ---- BN finalize: reduce 2048-block partials, one block per channel ----
__global__ void kbnf(const float* __restrict__ part, const float* __restrict__ gamma,
                     const float* __restrict__ beta, float* __restrict__ stats) {
  __shared__ float r1[256], r2[256];
  int o = blockIdx.x;
  int tid = threadIdx.x;
  float s1 = 0.f, s2 = 0.f;
  for (int i = tid; i < 2048; i += 256) {
    s1 += part[(size_t)i * 128 + o];
    s2 += part[(size_t)i * 128 + 64 + o];
  }
  r1[tid] = s1; r2[tid] = s2;
  __syncthreads();
  for (int s = 128; s > 0; s >>= 1) {
    if (tid < s) { r1[tid] += r1[tid + s]; r2[tid] += r2[tid + s]; }
    __syncthreads();
  }
  if (tid == 0) {
    float m = r1[0] * (1.f / 131072.f);
    float v = r2[0] * (1.f / 131072.f) - m * m;
    float sc = gamma[o] * rsqrtf(v + 1e-5f);
    stats[128 + o] = sc;
    stats[192 + o] = beta[o] - m * sc;
  }
}

// ---- final: read bf16 yb, scale/shift + PReLU, write f32 d_out ----
__global__ void kfinal(const u16* __restrict__ yb, float* __restrict__ y,
                       const float* __restrict__ stats, const float* __restrict__ pa) {
  float a = pa[0];
  int total = NPIX * 64 / 8;            // u16x8 chunks
  for (int i = blockIdx.x * blockDim.x + threadIdx.x; i < total;
       i += gridDim.x * blockDim.x) {
    int o = (i >> 11) & 63;             // (i*8 >> 14) & 63
    u32x4 v = ((const u32x4*)yb)[i];
    float sc = stats[128 + o], sh = stats[192 + o];
    f32x4 o0, o1;
#pragma unroll
    for (int j = 0; j < 4; ++j) {
      float tL = fmaf(bflo(v[j]), sc, sh);
      float tH = fmaf(bfhi(v[j]), sc, sh);
      float rL = tL >= 0.f ? tL : a * tL;
      float rH = tH >= 0.f ? tH : a * tH;
      if (j < 2) { o0[2 * j] = rL; o0[2 * j + 1] = rH; }
      else       { o1[2 * (j - 2)] = rL; o1[2 * (j - 2) + 1] = rH; }
    }
    ((f32x4*)y)[2 * i] = o0;
    ((f32x4*)y)[2 * i + 1] = o1;
  }
}

extern "C" void kernel_launch(void* const* d_in, const int* in_sizes, int n_in,
                              void* d_out, int out_size, void* d_ws, size_t ws_size,
                              hipStream_t stream) {
  const float* x  = (const float*)d_in[0];
  const float* ow = (const float*)d_in[1];
  const float* ob = (const float*)d_in[2];
  const float* dw = (const float*)d_in[3];
  const float* db = (const float*)d_in[4];
  const float* gm = (const float*)d_in[5];
  const float* bt = (const float*)d_in[6];
  const float* pa = (const float*)d_in[7];
  char* ws = (char*)d_ws;
  u16*   xt    = (u16*)(ws + XT_OFF);
  u16*   yb    = (u16*)(ws + YB_OFF);
  float* part  = (float*)(ws + PART_OFF);
  u16*   Wb    = (u16*)(ws + WB_OFF);
  u16*   Wo    = (u16*)(ws + WO_OFF);
  float* stats = (float*)(ws + STATS_OFF);
  float* y = (float*)d_out;

  kprep<<<216, 256, 0, stream>>>(dw, ow, Wb, Wo);
  ktrans<<<2048, 256, 0, stream>>>(x, xt);
  kmain<<<2048, 256, 0, stream>>>(xt, Wo, ob, Wb, db, yb, part);
  kbnf<<<64, 256, 0, stream>>>(part, gm, bt, stats);
  kfinal<<<2048, 256, 0, stream>>>(yb, y, stats, pa);
}

// Round 25
// 92.171 us; speedup vs baseline: 1.0398x; 1.0398x over previous
//
#include <hip/hip_runtime.h>
#include <hip/hip_bf16.h>
#include <hip/hip_fp16.h>

typedef float f32x4 __attribute__((ext_vector_type(4)));
typedef unsigned int u32;
typedef u32 u32x4 __attribute__((ext_vector_type(4)));
typedef __bf16 bf16x8 __attribute__((ext_vector_type(8)));
typedef short s16x8 __attribute__((ext_vector_type(8)));
typedef unsigned short u16;

#define HWSZ 16384
#define NPIX 131072

// ws byte offsets
#define XT_OFF    0u          // u16(bf16)[NPIX*64]  x transposed to NHWC (16.78 MB)
#define YB_OFF    16777216u   // u16(bf16)[NPIX*64]  pre-BN activation, NCHW (16.78 MB)
#define PART_OFF  33554432u   // float[1024*128]  per-block BN partials (512 KB)
#define WB_OFF    42991616u   // u16(bf16)[64*576]  deform_w, [o][k2*64+c]
#define STATS_OFF 43106816u   // float[256]: (unused)[128], scale[64], shift[64]
#define WO_OFF    43107840u   // u16(bf16)[32*576]  offset_w padded, [oc][k2*64+c]

__device__ inline u32 pkbf(float lo, float hi) {
  u16 l = __builtin_bit_cast(u16, __float2bfloat16(lo));
  u16 h = __builtin_bit_cast(u16, __float2bfloat16(hi));
  return (u32)l | ((u32)h << 16);
}
__device__ inline float bflo(u32 u) { return __builtin_bit_cast(float, u << 16); }
__device__ inline float bfhi(u32 u) { return __builtin_bit_cast(float, u & 0xFFFF0000u); }

// ---- prep: reorder/convert weights to bf16 ----
__global__ void kprep(const float* __restrict__ dw, const float* __restrict__ ow,
                      u16* __restrict__ Wb, u16* __restrict__ Wo) {
  int t = blockIdx.x * 256 + threadIdx.x;
  if (t < 36864) {                      // deform_w (64,64,3,3) -> Wb[o][k2*64+c] bf16
    int o = t / 576, r = t % 576;
    int c = r / 9, k2 = r % 9;
    __hip_bfloat16 h = __float2bfloat16(dw[t]);
    Wb[o * 576 + k2 * 64 + c] = __builtin_bit_cast(u16, h);
  } else if (t < 55296) {               // offset_w (18,64,3,3) -> Wo[oc][k2*64+c], pad to 32
    int t2 = t - 36864;
    int oc = t2 / 576, r = t2 % 576;
    int c = r / 9, k2 = r % 9;
    float v = (oc < 18) ? ow[(oc * 64 + c) * 9 + k2] : 0.f;
    __hip_bfloat16 h = __float2bfloat16(v);
    Wo[oc * 576 + k2 * 64 + c] = __builtin_bit_cast(u16, h);
  }
}

// ---- NCHW f32 -> NHWC bf16 transpose of x (vectorized 16B stores) ----
__global__ void ktrans(const float* __restrict__ x, u16* __restrict__ xt) {
  __shared__ float tile[64][65];
  int blk = blockIdx.x;
  int b = blk >> 8, hwT = (blk & 255) * 64;
  int tid = threadIdx.x;
  int tx = tid & 63, ty = tid >> 6;
  const float* xp = x + (size_t)b * 64 * HWSZ;
#pragma unroll
  for (int r = 0; r < 16; ++r) {
    int c = r * 4 + ty;
    tile[c][tx] = xp[c * HWSZ + hwT + tx];
  }
  __syncthreads();
  u16* xo = xt + ((size_t)b * HWSZ + hwT) * 64;
  int o8 = (tid & 7) * 8;
#pragma unroll
  for (int r = 0; r < 2; ++r) {
    int hwl = r * 32 + (tid >> 3);
    u32x4 out;
#pragma unroll
    for (int j = 0; j < 4; ++j)
      out[j] = pkbf(tile[o8 + 2 * j][hwl], tile[o8 + 2 * j + 1][hwl]);
    *(u32x4*)&xo[(size_t)hwl * 64 + o8] = out;
  }
}

// ---- fused, tap-pipelined, 128-px tile (one image row per block) ----
// block: 256 thr = 4 waves; LDS: S2 32768 + mWp 9216 + mPos 4608 = 46592 B
__global__ __launch_bounds__(256, 4) void kmain(
    const u16* __restrict__ xt, const u16* __restrict__ Wo,
    const float* __restrict__ offb, const u16* __restrict__ Wb,
    const float* __restrict__ db, u16* __restrict__ yb,
    float* __restrict__ part) {
  __shared__ u16 S2[2][128 * 64];      // per-tap staging, XOR-swizzled per 64ch row
  __shared__ u32 mWp[1152 * 2];        // per (pix,tap): f16x2 {w00,w01},{w10,w11}
  __shared__ u32 mPos[1152];           // pixel_byte(×128) | dxs | dys<<1
  float* OFFT = (float*)&S2[0][0];     // [128][20] floats, aliases S2[0]
  int tid = threadIdx.x;
  int lane = tid & 63, wid = tid >> 6;
  int bid = blockIdx.x;
  int batch = bid & 7, tilei = bid >> 3;
  int base = (batch << 14) + tilei * 128;   // whole row h0 = tilei, w0 = 0
  int b = batch;
  int h0 = tilei;

  int oct = lane & 7;
  int p0 = wid * 8 + (lane >> 3);      // this thread's pixels: p0 + {0,32,64,96}
  int oct16 = oct << 4, oct8 = oct << 3;
  int q8 = (lane >> 4) * 8;
  const char* xb = (const char*)xt;

  // ---- phase 1: offset-conv GEMM, tap-pipelined ----
  // wave w: oc-block (w&1), px-blocks (w>>1)*4 .. +3
  int ocb2 = wid & 1, pxb4 = (wid >> 1) * 4;
  int orow_o = ocb2 * 16 + (lane & 15);
  f32x4 acco[4];
#pragma unroll
  for (int t2 = 0; t2 < 4; ++t2) acco[t2] = {0.f, 0.f, 0.f, 0.f};
#pragma unroll
  for (int k = 0; k < 9; ++k) {
#pragma unroll
    for (int pi = 0; pi < 4; ++pi) {   // im2col tap k for 4 pixels
      int pp = p0 + pi * 32;
      int yy = h0 - 1 + k / 3, xx = pp - 1 + k % 3;
      bool v = ((unsigned)yy < 128u) && ((unsigned)xx < 128u);
      const char* pb =
          v ? xb + (size_t)(((b << 14) + yy * 128 + xx) * 128) + oct16 : xb;
      u32x4 g = *(const u32x4*)pb;
      u32 msk = v ? 0xFFFFFFFFu : 0u;
      u32x4 out;
#pragma unroll
      for (int j = 0; j < 4; ++j) out[j] = g[j] & msk;
      *(u32x4*)&S2[k & 1][(pp * 64 + oct8) ^ ((pp & 7) << 3)] = out;
    }
    __syncthreads();
#pragma unroll
    for (int h = 0; h < 2; ++h) {
      int kc = 2 * k + h;
      s16x8 a = *(const s16x8*)(Wo + orow_o * 576 + kc * 32 + q8);
#pragma unroll
      for (int t2 = 0; t2 < 4; ++t2) {
        int row = (pxb4 + t2) * 16 + (lane & 15);
        int idx = (row * 64 + h * 32 + q8) ^ ((row & 7) << 3);
        bf16x8 bb = __builtin_bit_cast(bf16x8, *(const s16x8*)&S2[k & 1][idx]);
        acco[t2] = __builtin_amdgcn_mfma_f32_16x16x32_bf16(
            __builtin_bit_cast(bf16x8, a), bb, acco[t2], 0, 0, 0);
      }
    }
  }
  __syncthreads();                     // S2 dead; OFFT may now be written

  // ---- offs -> OFFT (aliases S2[0]) ----
#pragma unroll
  for (int t2 = 0; t2 < 4; ++t2) {
    int pixl = (pxb4 + t2) * 16 + (lane & 15);
    int ocb = ocb2 * 16 + (lane >> 4) * 4;
#pragma unroll
    for (int r = 0; r < 4; ++r) {
      int oc = ocb + r;
      if (oc < 18) OFFT[pixl * 20 + oc] = acco[t2][r] + offb[oc];
    }
  }
  __syncthreads();

  // ---- meta: per-(pixel,tap), 1152 tasks ----
  for (int t = tid; t < 1152; t += 256) {
    int tp = t / 9, k2 = t - tp * 9;
    int pix = base + tp;
    int hw = pix & 16383;
    int hh = hw >> 7, ww = hw & 127;
    float dy = OFFT[tp * 20 + 2 * k2];
    float dx = OFFT[tp * 20 + 2 * k2 + 1];
    float sy = (float)(hh - 1 + k2 / 3) + dy;
    float sx = (float)(ww - 1 + k2 % 3) + dx;
    float fy = floorf(sy), fx = floorf(sx);
    int y0 = (int)fy, x0 = (int)fx;
    float wy1 = sy - fy, wx1 = sx - fx;
    float ay0 = ((unsigned)y0 < 128u) ? 1.f - wy1 : 0.f;
    float ay1 = ((unsigned)(y0 + 1) < 128u) ? wy1 : 0.f;
    float ax0 = ((unsigned)x0 < 128u) ? 1.f - wx1 : 0.f;
    float ax1 = ((unsigned)(x0 + 1) < 128u) ? wx1 : 0.f;
    int y0c = min(max(y0, 0), 127), x0c = min(max(x0, 0), 127);
    int dys = min(max(y0 + 1, 0), 127) - y0c;
    int dxs = min(max(x0 + 1, 0), 127) - x0c;
    mWp[t * 2]     = __builtin_bit_cast(u32, __floats2half2_rn(ay0 * ax0, ay0 * ax1));
    mWp[t * 2 + 1] = __builtin_bit_cast(u32, __floats2half2_rn(ay1 * ax0, ay1 * ax1));
    mPos[t] = (u32)(((b << 14) + y0c * 128 + x0c) * 128) | (u32)dxs | ((u32)dys << 1);
  }
  __syncthreads();                     // meta done; S2[0] (OFFT) may be overwritten

  // ---- phase 2: deform GEMM, tap-pipelined sampling ----
  // wave w: o-rows 16w..16w+15, all 8 px-blocks
  f32x4 acc[8];
#pragma unroll
  for (int nb = 0; nb < 8; ++nb) acc[nb] = {0.f, 0.f, 0.f, 0.f};
  int orow_d = wid * 16 + (lane & 15);
#pragma unroll
  for (int k = 0; k < 9; ++k) {
#pragma unroll
    for (int pi = 0; pi < 4; ++pi) {   // sample tap k for 4 pixels
      int pp = p0 + pi * 32;
      int t = pp * 9 + k;
      u32 wlo = mWp[t * 2], whi = mWp[t * 2 + 1];
      u32 pm = mPos[t];
      u32 dxB = (pm & 1u) << 7;        // 128 B x-step
      u32 dyB = (pm & 2u) << 13;       // 16384 B y-step
      const char* pb = xb + (pm & 0xFFFFFF80u) + oct16;
      u32x4 c00 = *(const u32x4*)pb;
      u32x4 c01 = *(const u32x4*)(pb + dxB);
      u32x4 c10 = *(const u32x4*)(pb + dyB);
      u32x4 c11 = *(const u32x4*)(pb + dyB + dxB);
      __half2 hl = __builtin_bit_cast(__half2, wlo);
      __half2 hh2 = __builtin_bit_cast(__half2, whi);
      float w00 = __low2float(hl), w01 = __high2float(hl);
      float w10 = __low2float(hh2), w11 = __high2float(hh2);
      u32x4 out;
#pragma unroll
      for (int j = 0; j < 4; ++j) {
        float sL = fmaf(w11, bflo(c11[j]), fmaf(w10, bflo(c10[j]),
                   fmaf(w01, bflo(c01[j]), w00 * bflo(c00[j]))));
        float sH = fmaf(w11, bfhi(c11[j]), fmaf(w10, bfhi(c10[j]),
                   fmaf(w01, bfhi(c01[j]), w00 * bfhi(c00[j]))));
        out[j] = pkbf(sL, sH);
      }
      *(u32x4*)&S2[k & 1][(pp * 64 + oct8) ^ ((pp & 7) << 3)] = out;
    }
    __syncthreads();
#pragma unroll
    for (int h = 0; h < 2; ++h) {
      int kc = 2 * k + h;
      s16x8 a = *(const s16x8*)(Wb + orow_d * 576 + kc * 32 + q8);
#pragma unroll
      for (int nb = 0; nb < 8; ++nb) {
        int row = nb * 16 + (lane & 15);
        int idx = (row * 64 + h * 32 + q8) ^ ((row & 7) << 3);
        bf16x8 bb = __builtin_bit_cast(bf16x8, *(const s16x8*)&S2[k & 1][idx]);
        acc[nb] = __builtin_amdgcn_mfma_f32_16x16x32_bf16(
            __builtin_bit_cast(bf16x8, a), bb, acc[nb], 0, 0, 0);
      }
    }
  }

  // ---- epilogue: yb (bf16, NCHW) write + per-block BN partials (no atomics) ----
  int obase = wid * 16 + (lane >> 4) * 4;
  float s1[4] = {0, 0, 0, 0}, s2[4] = {0, 0, 0, 0};
#pragma unroll
  for (int nb = 0; nb < 8; ++nb) {
    int pix = base + nb * 16 + (lane & 15);
    int hw = pix & 16383;
    u16* yp = yb + (size_t)b * (64 * HWSZ) + hw;
#pragma unroll
    for (int r = 0; r < 4; ++r) {
      int o = obase + r;
      float v = acc[nb][r] + db[o];
      yp[(size_t)o * HWSZ] = __builtin_bit_cast(u16, __float2bfloat16(v));
      s1[r] += v;
      s2[r] += v * v;
    }
  }
#pragma unroll
  for (int m = 1; m < 16; m <<= 1) {
#pragma unroll
    for (int r = 0; r < 4; ++r) {
      s1[r] += __shfl_xor(s1[r], m, 64);
      s2[r] += __shfl_xor(s2[r], m, 64);
    }
  }
  if ((lane & 15) == 0) {
    float* pp = part + (size_t)bid * 128;
#pragma unroll
    for (int r = 0; r < 4; ++r) {
      pp[obase + r] = s1[r];
      pp[64 + obase + r] = s2[r];
    }
  }
}

// ---- BN finalize: reduce 1024-block partials, one block per channel ----
__global__ void kbnf(const float* __restrict__ part, const float* __restrict__ gamma,
                     const float* __restrict__ beta, float* __restrict__ stats) {
  __shared__ float r1[256], r2[256];
  int o = blockIdx.x;
  int tid = threadIdx.x;
  float s1 = 0.f, s2 = 0.f;
  for (int i = tid; i < 1024; i += 256) {
    s1 += part[(size_t)i * 128 + o];
    s2 += part[(size_t)i * 128 + 64 + o];
  }
  r1[tid] = s1; r2[tid] = s2;
  __syncthreads();
  for (int s = 128; s > 0; s >>= 1) {
    if (tid < s) { r1[tid] += r1[tid + s]; r2[tid] += r2[tid + s]; }
    __syncthreads();
  }
  if (tid == 0) {
    float m = r1[0] * (1.f / 131072.f);
    float v = r2[0] * (1.f / 131072.f) - m * m;
    float sc = gamma[o] * rsqrtf(v + 1e-5f);
    stats[128 + o] = sc;
    stats[192 + o] = beta[o] - m * sc;
  }
}

// ---- final: read bf16 yb, scale/shift + PReLU, write f32 d_out ----
__global__ void kfinal(const u16* __restrict__ yb, float* __restrict__ y,
                       const float* __restrict__ stats, const float* __restrict__ pa) {
  float a = pa[0];
  int total = NPIX * 64 / 8;            // u16x8 chunks
  for (int i = blockIdx.x * blockDim.x + threadIdx.x; i < total;
       i += gridDim.x * blockDim.x) {
    int o = (i >> 11) & 63;             // (i*8 >> 14) & 63
    u32x4 v = ((const u32x4*)yb)[i];
    float sc = stats[128 + o], sh = stats[192 + o];
    f32x4 o0, o1;
#pragma unroll
    for (int j = 0; j < 4; ++j) {
      float tL = fmaf(bflo(v[j]), sc, sh);
      float tH = fmaf(bfhi(v[j]), sc, sh);
      float rL = tL >= 0.f ? tL : a * tL;
      float rH = tH >= 0.f ? tH : a * tH;
      if (j < 2) { o0[2 * j] = rL; o0[2 * j + 1] = rH; }
      else       { o1[2 * (j - 2)] = rL; o1[2 * (j - 2) + 1] = rH; }
    }
    ((f32x4*)y)[2 * i] = o0;
    ((f32x4*)y)[2 * i + 1] = o1;
  }
}

extern "C" void kernel_launch(void* const* d_in, const int* in_sizes, int n_in,
                              void* d_out, int out_size, void* d_ws, size_t ws_size,
                              hipStream_t stream) {
  const float* x  = (const float*)d_in[0];
  const float* ow = (const float*)d_in[1];
  const float* ob = (const float*)d_in[2];
  const float* dw = (const float*)d_in[3];
  const float* db = (const float*)d_in[4];
  const float* gm = (const float*)d_in[5];
  const float* bt = (const float*)d_in[6];
  const float* pa = (const float*)d_in[7];
  char* ws = (char*)d_ws;
  u16*   xt    = (u16*)(ws + XT_OFF);
  u16*   yb    = (u16*)(ws + YB_OFF);
  float* part  = (float*)(ws + PART_OFF);
  u16*   Wb    = (u16*)(ws + WB_OFF);
  u16*   Wo    = (u16*)(ws + WO_OFF);
  float* stats = (float*)(ws + STATS_OFF);
  float* y = (float*)d_out;

  kprep<<<216, 256, 0, stream>>>(dw, ow, Wb, Wo);
  ktrans<<<2048, 256, 0, stream>>>(x, xt);
  kmain<<<1024, 256, 0, stream>>>(xt, Wo, ob, Wb, db, yb, part);
  kbnf<<<64, 256, 0, stream>>>(part, gm, bt, stats);
  kfinal<<<2048, 256, 0, stream>>>(yb, y, stats, pa);
}